// Round 8
// baseline (1034.300 us; speedup 1.0000x reference)
//
#include <hip/hip_runtime.h>
#include <math.h>

#define BATCH 2048
#define FID 65536
#define NT 256
#define ROWS 4                 // rows per block: bias vf4 reused 4x
#define NV (FID / 4)           // 16384 vf4 per row
#define KSPLIT 4
#define NVH (NV / KSPLIT)      // 4096 vf4 per block per row
#define NBLOCKS ((BATCH / ROWS) * KSPLIT)

typedef float vf4 __attribute__((ext_vector_type(4)));

// R8: best config (R6: nt loads, unroll 2, lb(256,8), KSPLIT=4) + finisher
// merged via last-block-done (threadfence + atomic counter in d_ws).
// Removes one graph node (~5 us dispatch overhead).
__global__ __launch_bounds__(NT, 8) void lr_fused(
        const float* __restrict__ gate,
        const float* __restrict__ bias,
        const float* __restrict__ gbias,
        const float* __restrict__ label,
        float* __restrict__ out,            // [logits | pred | loss]; logits pre-zeroed
        unsigned int* __restrict__ done) {  // pre-zeroed counter in d_ws
    const int kb = blockIdx.x & (KSPLIT - 1);
    const int rb = blockIdx.x >> 2;
    const int r0 = rb * ROWS;
    const vf4* __restrict__ b4 = (const vf4*)bias;
    const vf4* __restrict__ g4 = (const vf4*)gate + (size_t)r0 * NV;
    const int i0 = kb * NVH;
    const int i1 = i0 + NVH;

    float a0 = 0.f, a1 = 0.f, a2 = 0.f, a3 = 0.f;

    #pragma unroll 2
    for (int i = i0 + threadIdx.x; i < i1; i += NT) {
        vf4 v  = b4[i];
        vf4 g0 = __builtin_nontemporal_load(&g4[i]);
        vf4 g1 = __builtin_nontemporal_load(&g4[i + NV]);
        vf4 g2 = __builtin_nontemporal_load(&g4[i + 2 * NV]);
        vf4 g3 = __builtin_nontemporal_load(&g4[i + 3 * NV]);
        a0 = fmaf(g0.x, v.x, a0); a0 = fmaf(g0.y, v.y, a0);
        a0 = fmaf(g0.z, v.z, a0); a0 = fmaf(g0.w, v.w, a0);
        a1 = fmaf(g1.x, v.x, a1); a1 = fmaf(g1.y, v.y, a1);
        a1 = fmaf(g1.z, v.z, a1); a1 = fmaf(g1.w, v.w, a1);
        a2 = fmaf(g2.x, v.x, a2); a2 = fmaf(g2.y, v.y, a2);
        a2 = fmaf(g2.z, v.z, a2); a2 = fmaf(g2.w, v.w, a2);
        a3 = fmaf(g3.x, v.x, a3); a3 = fmaf(g3.y, v.y, a3);
        a3 = fmaf(g3.z, v.z, a3); a3 = fmaf(g3.w, v.w, a3);
    }

    #pragma unroll
    for (int off = 32; off > 0; off >>= 1) {
        a0 += __shfl_down(a0, off, 64);
        a1 += __shfl_down(a1, off, 64);
        a2 += __shfl_down(a2, off, 64);
        a3 += __shfl_down(a3, off, 64);
    }

    __shared__ float wsum[NT / 64][ROWS];
    __shared__ bool amLast;
    const int wave = threadIdx.x >> 6;
    const int lane = threadIdx.x & 63;
    if (lane == 0) {
        wsum[wave][0] = a0; wsum[wave][1] = a1;
        wsum[wave][2] = a2; wsum[wave][3] = a3;
    }
    __syncthreads();

    if (threadIdx.x < ROWS) {
        const int r = threadIdx.x;
        float s = wsum[0][r] + wsum[1][r] + wsum[2][r] + wsum[3][r];
        atomicAdd(&out[r0 + r], s);
    }

    // last-block-done: device-scope fence so all atomics are visible, then
    // the final block performs the epilogue (gbias add, pred, loss).
    __threadfence();
    if (threadIdx.x == 0)
        amLast = (atomicAdd(done, 1u) == NBLOCKS - 1);
    __syncthreads();

    if (amLast) {
        const float gb = gbias[0];
        float acc = 0.0f;
        for (int i = threadIdx.x; i < BATCH; i += NT) {
            float x = out[i] + gb;
            float l = label[i];
            out[i] = x;                                 // final logit
            out[BATCH + i] = 1.0f / (1.0f + expf(-x));  // pred
            acc += fmaxf(x, 0.0f) - x * l + log1pf(expf(-fabsf(x)));
        }
        #pragma unroll
        for (int off = 32; off > 0; off >>= 1)
            acc += __shfl_down(acc, off, 64);
        __syncthreads();  // reuse wsum
        if (lane == 0) wsum[wave][0] = acc;
        __syncthreads();
        if (threadIdx.x == 0)
            out[2 * BATCH] = wsum[0][0] + wsum[1][0] + wsum[2][0] + wsum[3][0];
    }
}

extern "C" void kernel_launch(void* const* d_in, const int* in_sizes, int n_in,
                              void* d_out, int out_size, void* d_ws, size_t ws_size,
                              hipStream_t stream) {
    const float* gate  = (const float*)d_in[0];  // [BATCH, FID]
    const float* bias  = (const float*)d_in[1];  // [FID]
    const float* gbias = (const float*)d_in[2];  // [1]
    const float* label = (const float*)d_in[3];  // [BATCH]
    float* out = (float*)d_out;                  // [logits | pred | loss]
    unsigned int* done = (unsigned int*)d_ws;    // completion counter

    // Zero atomic targets (d_out/d_ws poisoned 0xAA before every launch).
    hipMemsetAsync(out, 0, BATCH * sizeof(float), stream);
    hipMemsetAsync(done, 0, sizeof(unsigned int), stream);

    lr_fused<<<NBLOCKS, NT, 0, stream>>>(gate, bias, gbias, label, out, done);
}

// Round 9
// 649.278 us; speedup vs baseline: 1.5930x; 1.5930x over previous
//
#include <hip/hip_runtime.h>
#include <math.h>

#define BATCH 2048
#define FID 65536
#define NT 256
#define ROWS 4                 // rows per block: bias vf4 reused 4x
#define NV (FID / 4)           // 16384 vf4 per row
#define KSPLIT 4
#define NVH (NV / KSPLIT)      // 4096 vf4 per block per row

typedef float vf4 __attribute__((ext_vector_type(4)));

// R9 = revert to R6 (best: 650 us, tied with R4). nt gate loads (keep the
// dead 512 MiB stream out of L2 allocation: removing nt cost +29 us in R7),
// unroll 2 + lb(256,8) for 32 waves/CU, KSPLIT=4 -> 2048 blocks (whole grid
// resident). R8's fused last-block-done variant regressed 650->1034: its
// device-scope __threadfence lowers to L2 writeback/invalidate per block
// (per-XCD L2 non-coherence), flushing L2 continuously -> 560 GB/s.
__global__ __launch_bounds__(NT, 8) void lr_partial(
        const float* __restrict__ gate,
        const float* __restrict__ bias,
        float* __restrict__ out) {          // logits region, pre-zeroed
    const int kb = blockIdx.x & (KSPLIT - 1);
    const int rb = blockIdx.x >> 2;
    const int r0 = rb * ROWS;
    const vf4* __restrict__ b4 = (const vf4*)bias;
    const vf4* __restrict__ g4 = (const vf4*)gate + (size_t)r0 * NV;
    const int i0 = kb * NVH;
    const int i1 = i0 + NVH;

    float a0 = 0.f, a1 = 0.f, a2 = 0.f, a3 = 0.f;

    #pragma unroll 2
    for (int i = i0 + threadIdx.x; i < i1; i += NT) {
        vf4 v  = b4[i];
        vf4 g0 = __builtin_nontemporal_load(&g4[i]);
        vf4 g1 = __builtin_nontemporal_load(&g4[i + NV]);
        vf4 g2 = __builtin_nontemporal_load(&g4[i + 2 * NV]);
        vf4 g3 = __builtin_nontemporal_load(&g4[i + 3 * NV]);
        a0 = fmaf(g0.x, v.x, a0); a0 = fmaf(g0.y, v.y, a0);
        a0 = fmaf(g0.z, v.z, a0); a0 = fmaf(g0.w, v.w, a0);
        a1 = fmaf(g1.x, v.x, a1); a1 = fmaf(g1.y, v.y, a1);
        a1 = fmaf(g1.z, v.z, a1); a1 = fmaf(g1.w, v.w, a1);
        a2 = fmaf(g2.x, v.x, a2); a2 = fmaf(g2.y, v.y, a2);
        a2 = fmaf(g2.z, v.z, a2); a2 = fmaf(g2.w, v.w, a2);
        a3 = fmaf(g3.x, v.x, a3); a3 = fmaf(g3.y, v.y, a3);
        a3 = fmaf(g3.z, v.z, a3); a3 = fmaf(g3.w, v.w, a3);
    }

    #pragma unroll
    for (int off = 32; off > 0; off >>= 1) {
        a0 += __shfl_down(a0, off, 64);
        a1 += __shfl_down(a1, off, 64);
        a2 += __shfl_down(a2, off, 64);
        a3 += __shfl_down(a3, off, 64);
    }

    __shared__ float wsum[NT / 64][ROWS];
    const int wave = threadIdx.x >> 6;
    const int lane = threadIdx.x & 63;
    if (lane == 0) {
        wsum[wave][0] = a0; wsum[wave][1] = a1;
        wsum[wave][2] = a2; wsum[wave][3] = a3;
    }
    __syncthreads();

    if (threadIdx.x < ROWS) {
        const int r = threadIdx.x;
        float s = wsum[0][r] + wsum[1][r] + wsum[2][r] + wsum[3][r];
        atomicAdd(&out[r0 + r], s);
    }
}

// Finisher: add gbias, write final logits + pred, reduce loss. One block.
__global__ __launch_bounds__(NT) void lr_finish(
        const float* __restrict__ gbias,
        const float* __restrict__ label,
        float* __restrict__ out) {
    const float gb = gbias[0];
    float acc = 0.0f;
    for (int i = threadIdx.x; i < BATCH; i += NT) {
        float x = out[i] + gb;
        float l = label[i];
        out[i] = x;                                 // final logit
        out[BATCH + i] = 1.0f / (1.0f + expf(-x));  // pred
        acc += fmaxf(x, 0.0f) - x * l + log1pf(expf(-fabsf(x)));
    }
    #pragma unroll
    for (int off = 32; off > 0; off >>= 1)
        acc += __shfl_down(acc, off, 64);

    __shared__ float wsum[NT / 64];
    const int wave = threadIdx.x >> 6;
    const int lane = threadIdx.x & 63;
    if (lane == 0) wsum[wave] = acc;
    __syncthreads();
    if (threadIdx.x == 0)
        out[2 * BATCH] = wsum[0] + wsum[1] + wsum[2] + wsum[3];
}

extern "C" void kernel_launch(void* const* d_in, const int* in_sizes, int n_in,
                              void* d_out, int out_size, void* d_ws, size_t ws_size,
                              hipStream_t stream) {
    const float* gate  = (const float*)d_in[0];  // [BATCH, FID]
    const float* bias  = (const float*)d_in[1];  // [FID]
    const float* gbias = (const float*)d_in[2];  // [1]
    const float* label = (const float*)d_in[3];  // [BATCH]
    float* out = (float*)d_out;                  // [logits | pred | loss]

    // logits region is atomicAdd target -> zero it (d_out is poisoned 0xAA
    // before every timed launch). 8 KB, captured as a memset node.
    hipMemsetAsync(out, 0, BATCH * sizeof(float), stream);

    lr_partial<<<(BATCH / ROWS) * KSPLIT, NT, 0, stream>>>(gate, bias, out);
    lr_finish<<<1, NT, 0, stream>>>(gbias, label, out);
}